// Round 9
// baseline (142.636 us; speedup 1.0000x reference)
//
#include <hip/hip_runtime.h>

typedef short v8s __attribute__((ext_vector_type(8)));
typedef float v4f __attribute__((ext_vector_type(4)));
typedef float v16f __attribute__((ext_vector_type(16)));

// RNE float -> bf16 (matches float_quantize(exp=8, man=7) for these inputs).
__device__ __forceinline__ unsigned short rne_bf16(float f) {
  unsigned u = __float_as_uint(f);
  return (unsigned short)((u + 0x7fffu + ((u >> 16) & 1u)) >> 16);
}
__device__ __forceinline__ float qbf(float f) {
  return __uint_as_float(((unsigned)rne_bf16(f)) << 16);
}

__device__ __forceinline__ void gload_lds16(const void* g, void* l) {
  __builtin_amdgcn_global_load_lds((__attribute__((address_space(1))) void*)g,
                                   (__attribute__((address_space(3))) void*)l,
                                   16, 0, 0);
}

#define PCS 72  // prep LDS col stride (shorts)

// ---------------------------------------------------------------------------
// prep (verbatim from R8, verified): quantize+transpose x -> Xp[b][58][col]
// with slot = c8 ^ (col&7) pre-swizzle (T2/m173 rule #21) and zeroed borders;
// blocks 1792..1823 reorder weights into fragment-major Wt2.
// ---------------------------------------------------------------------------
__global__ __launch_bounds__(256) void prep(const float* __restrict__ x,
                                            const float* __restrict__ w,
                                            unsigned short* __restrict__ Xp,
                                            unsigned short* __restrict__ Wt2) {
  const int blk = blockIdx.x;
  const int tid = threadIdx.x;

  if (blk >= 1792) {  // ---- weight reorder ----
    int t = (blk - 1792) * 256 + tid;  // 0..8191 = n*64 + c
    int n = t >> 6, c = t & 63;
    int kk = c >> 4;
    int lane = (n & 31) + 32 * ((c >> 3) & 1);
    const float* src = w + (size_t)t * 9;
#pragma unroll
    for (int pos = 0; pos < 9; ++pos) {
      int idx = (((pos * 4 + kk) * 4 + (n >> 5)) << 9) + lane * 8 + (c & 7);
      Wt2[idx] = rne_bf16(src[pos]);
    }
    return;
  }

  const int b = blk / 56, h = blk % 56;
  __shared__ __align__(16) unsigned short tile[56 * PCS];  // [w][c]

  unsigned short* rowp = Xp + (((size_t)b * 58 + (h + 1)) * 58) * 64;
  if (tid < 64) { rowp[tid] = 0; rowp[57 * 64 + tid] = 0; }
  if (h == 0) {
    unsigned short* r0 = Xp + ((size_t)b * 58 * 58) * 64;
    unsigned short* r57 = r0 + (size_t)57 * 58 * 64;
    for (int i = tid; i < 58 * 64; i += 256) { r0[i] = 0; r57[i] = 0; }
  }

#pragma unroll
  for (int it = 0; it < 2; ++it) {
    int i = it * 256 + tid;
    if (i < 448) {
      int c8 = i / 56, ww = i - c8 * 56;
      const float* xb = x + ((size_t)(b * 64 + c8 * 8)) * 3136 + h * 56 + ww;
      v8s pk;
#pragma unroll
      for (int j = 0; j < 8; ++j) pk[j] = (short)rne_bf16(xb[(size_t)j * 3136]);
      *(v8s*)&tile[ww * PCS + c8 * 8] = pk;
    }
  }
  __syncthreads();

  unsigned short* dst = Xp + (((size_t)b * 58 + (h + 1)) * 58 + 1) * 64;
#pragma unroll
  for (int it = 0; it < 2; ++it) {
    int i = it * 256 + tid;
    if (i < 448) {
      int ww = i >> 3, cb = i & 7;
      int slot = cb ^ ((ww + 1) & 7);  // col = ww+1 in padded coords
      *(v8s*)&dst[ww * 64 + slot * 8] = *(const v8s*)&tile[ww * PCS + cb * 8];
    }
  }
}

// ---------------------------------------------------------------------------
// conv, round 9: TRUE async pipeline (T3+T4). Block = 4 output rows (2 pairs)
// x 128 ch of one batch: tiles t0 (padded rows q..q+3) and t1 (q+2..q+5).
// Stage A = 32 KB (8 gload_lds16/wave), stage B = rows q+4,q+5 ONLY (16 KB,
// 4/wave; t1 reuses A's rows 2,3). Both issued at kernel start; raw barriers
// with COUNTED vmcnt keep B in flight under ladder(A):
//   barrier1: vmcnt(4)  -> A done, B's 4 still flying (never drain to 0)
//   barrier2: vmcnt(8)  -> B done, W-reload(8) still flying
// (all-but-youngest-N counts: robust to exec-masked loads + OoO completion,
// since vmcnt retires in issue order, m135.)  t0 stores fire under ladder(B).
// LDS 48.5 KB -> 3 blocks/CU = 12 waves/CU, all 448 blocks resident.
// XCD swizzle: 448 = 8*56, XCD x gets batches 4x..4x+3 (row-overlap L2 hits).
// Accumulation order per output chain identical to the verified kernel.
// ---------------------------------------------------------------------------
__global__ __launch_bounds__(256, 3) void conv(const unsigned short* __restrict__ Xp,
                                               const unsigned short* __restrict__ Wt2,
                                               const float* __restrict__ bias,
                                               float* __restrict__ out) {
  __shared__ __align__(16) char smem[32768 + 16384 + 512];
  char* bufA = smem;            // padded rows q..q+3 (+junk tail, never read)
  char* bufB = smem + 32768;    // padded rows q+4..q+5 (+junk tail)
  float* qb = (float*)(smem + 49152);  // 128 quantized biases

  const int id = blockIdx.x;
  const int orig = (id & 7) * 56 + (id >> 3);  // bijective XCD swizzle
  const int p2 = orig % 14, b = orig / 14;
  const int q = p2 * 4;  // top padded row of this block's 6-row window
  const int tid = threadIdx.x;
  const int wv = tid >> 6, lane = tid & 63;
  const int lj = lane & 31, lh = lane >> 5;
  const int lj1 = 28 + (lj < 27 ? lj : 27);  // sp-tile1 col offset (clamped)
  const int rw = wv & 1;                     // wave's output row within pair
  const int gg2 = (wv >> 1) * 2;             // wave's first 32-ch group

  float qbv = 0.0f;
  if (tid < 128) qbv = qbf(bias[tid]);

  const unsigned short* wt0 = Wt2 + lane * 8;
  v8s wa[4], wb[4];
#define WLOADH(POS, HALF, BUF)                                                 \
  {                                                                            \
    _Pragma("unroll") for (int kk2 = 0; kk2 < 2; ++kk2) {                      \
      _Pragma("unroll") for (int gi = 0; gi < 2; ++gi) {                       \
        BUF[kk2 * 2 + gi] = *(const v8s*)(                                     \
            wt0 + ((((POS)*4 + (HALF)*2 + kk2) * 4 + gg2 + gi) << 9));         \
      }                                                                        \
    }                                                                          \
  }
  WLOADH(0, 0, wa);
  WLOADH(0, 1, wb);

  asm volatile("" ::: "memory");  // pin: bias/W loads issue BEFORE the stages

  // ---- stage both tiles asynchronously (zero-VGPR, unsinkable) ----
  const char* srcA = (const char*)Xp + ((size_t)b * 58 + q) * 7424;
  const char* srcB = srcA + 4 * 7424;
#pragma unroll
  for (int it = 0; it < 8; ++it)
    gload_lds16(srcA + it * 4096 + tid * 16, bufA + it * 4096 + wv * 1024);
#pragma unroll
  for (int it = 0; it < 4; ++it)
    gload_lds16(srcB + it * 4096 + tid * 16, bufB + it * 4096 + wv * 1024);

  asm volatile("s_waitcnt vmcnt(4)" ::: "memory");  // A done; B still in flight
  __builtin_amdgcn_s_barrier();
  asm volatile("" ::: "memory");

  if (tid < 128) qb[tid] = qbv;  // LDS write; visible via barrier2's lgkmcnt

  v16f acc[2][2];  // [n-group][sp tile]
#define ACC_ZERO                                                               \
  _Pragma("unroll") for (int a = 0; a < 2; ++a)                                \
  _Pragma("unroll") for (int s = 0; s < 2; ++s)                                \
  _Pragma("unroll") for (int e = 0; e < 16; ++e) acc[a][s][e] = 0.0f;

  // read-side XOR matches prep's pre-swizzle: byte = col*128 + ((c8^(col&7))<<4)
#define COMPH(RB, POS, HALF, BUF)                                              \
  {                                                                            \
    const int kw = (POS) % 3;                                                  \
    const int col0 = kw + lj, col1 = kw + lj1;                                 \
    _Pragma("unroll") for (int kk2 = 0; kk2 < 2; ++kk2) {                      \
      const int c8f = lh + kk2 * 2 + (HALF)*4;                                 \
      v8s q0 = *(const v8s*)((RB) + col0 * 128 + ((c8f ^ (col0 & 7)) << 4));   \
      v8s q1 = *(const v8s*)((RB) + col1 * 128 + ((c8f ^ (col1 & 7)) << 4));   \
      _Pragma("unroll") for (int gi = 0; gi < 2; ++gi) {                       \
        acc[gi][0] = __builtin_amdgcn_mfma_f32_32x32x16_bf16(BUF[kk2 * 2 + gi], q0, acc[gi][0], 0, 0, 0); \
        acc[gi][1] = __builtin_amdgcn_mfma_f32_32x32x16_bf16(BUF[kk2 * 2 + gi], q1, acc[gi][1], 0, 0, 0); \
      }                                                                        \
    }                                                                          \
  }

  // pos 0-2 read row RB0, 3-5 RB1, 6-8 RB2 (kh bands)
#define LADDER3(RB0, RB1, RB2)                                                 \
  COMPH(RB0, 0, 0, wa); WLOADH(1, 0, wa); COMPH(RB0, 0, 1, wb); WLOADH(1, 1, wb); \
  COMPH(RB0, 1, 0, wa); WLOADH(2, 0, wa); COMPH(RB0, 1, 1, wb); WLOADH(2, 1, wb); \
  COMPH(RB0, 2, 0, wa); WLOADH(3, 0, wa); COMPH(RB0, 2, 1, wb); WLOADH(3, 1, wb); \
  COMPH(RB1, 3, 0, wa); WLOADH(4, 0, wa); COMPH(RB1, 3, 1, wb); WLOADH(4, 1, wb); \
  COMPH(RB1, 4, 0, wa); WLOADH(5, 0, wa); COMPH(RB1, 4, 1, wb); WLOADH(5, 1, wb); \
  COMPH(RB1, 5, 0, wa); WLOADH(6, 0, wa); COMPH(RB1, 5, 1, wb); WLOADH(6, 1, wb); \
  COMPH(RB2, 6, 0, wa); WLOADH(7, 0, wa); COMPH(RB2, 6, 1, wb); WLOADH(7, 1, wb); \
  COMPH(RB2, 7, 0, wa); WLOADH(8, 0, wa); COMPH(RB2, 7, 1, wb); WLOADH(8, 1, wb); \
  COMPH(RB2, 8, 0, wa); COMPH(RB2, 8, 1, wb);

  // ch = gg2*32 + gi*32 + (e&3)+8*(e>>2) + 4*lh  (C/D layout, verified)
#define STORES(OH)                                                             \
  if (lj < 28) {                                                               \
    float* ob = out + ((size_t)(b * 128 + gg2 * 32 + 4 * lh)) * 3136 +         \
                (size_t)(OH)*56 + lj;                                          \
    _Pragma("unroll") for (int gi = 0; gi < 2; ++gi) {                         \
      _Pragma("unroll") for (int e = 0; e < 16; ++e) {                         \
        const int chp = (e & 3) + 8 * (e >> 2);                                \
        float bb = qb[gg2 * 32 + gi * 32 + chp + 4 * lh];                      \
        float* d = ob + (size_t)(gi * 32 + chp) * 3136;                        \
        d[0] = acc[gi][0][e] + bb;                                             \
        d[28] = acc[gi][1][e] + bb;                                            \
      }                                                                        \
    }                                                                          \
  }

  // ================= tile 0 (rows q..q+3 in bufA) =================
  ACC_ZERO;
  LADDER3(bufA + rw * 7424, bufA + (rw + 1) * 7424, bufA + (rw + 2) * 7424);
  WLOADH(0, 0, wa);  // W reload for tile 1 (flies across barrier2)
  WLOADH(0, 1, wb);
  // B done (all-but-youngest-8 = everything except the W reload):
  asm volatile("s_waitcnt vmcnt(8) lgkmcnt(0)" ::: "memory");
  __builtin_amdgcn_s_barrier();
  asm volatile("" ::: "memory");

  STORES(q + rw);  // t0 stores fire-and-forget under ladder(B)

  // ================= tile 1 (rows q+2..q+5: bufA rows 2,3 + bufB) =========
  ACC_ZERO;
  LADDER3(bufA + (2 + rw) * 7424, rw ? bufB : bufA + 3 * 7424, bufB + rw * 7424);
  STORES(q + 2 + rw);
}

extern "C" void kernel_launch(void* const* d_in, const int* in_sizes, int n_in,
                              void* d_out, int out_size, void* d_ws, size_t ws_size,
                              hipStream_t stream) {
  const float* x = (const float*)d_in[0];     // [32,64,56,56]
  const float* w = (const float*)d_in[1];     // [128,64,3,3]
  const float* bias = (const float*)d_in[2];  // [128]
  float* out = (float*)d_out;                 // [32,128,56,56] fp32

  unsigned short* Xp = (unsigned short*)d_ws;              // 32*58*58*64 bf16
  const size_t XP_BYTES = (size_t)32 * 58 * 58 * 64 * 2;   // 13,778,944 B
  unsigned short* Wt2 = (unsigned short*)((char*)d_ws + XP_BYTES);  // 147 KB

  prep<<<1792 + 32, 256, 0, stream>>>(x, w, Xp, Wt2);
  conv<<<448, 256, 0, stream>>>(Xp, Wt2, bias, out);
}

// Round 10
// 115.387 us; speedup vs baseline: 1.2361x; 1.2361x over previous
//
#include <hip/hip_runtime.h>

typedef short v8s __attribute__((ext_vector_type(8)));
typedef float v4f __attribute__((ext_vector_type(4)));
typedef float v16f __attribute__((ext_vector_type(16)));

// RNE float -> bf16 (matches float_quantize(exp=8, man=7) for these inputs).
__device__ __forceinline__ unsigned short rne_bf16(float f) {
  unsigned u = __float_as_uint(f);
  return (unsigned short)((u + 0x7fffu + ((u >> 16) & 1u)) >> 16);
}
__device__ __forceinline__ float qbf(float f) {
  return __uint_as_float(((unsigned)rne_bf16(f)) << 16);
}

#define CS 72  // LDS col stride (shorts): 144 B; bank-benign (col*36 dwords)

// ---------------------------------------------------------------------------
// wprep: 32 blocks. weights -> fragment-major Wt2:
//   Wt2[((pos*4 + kk)*4 + g)*512 + lane*8 + (c&7)],  g = n>>5 (0..3)
//   lane = (n&31) + 32*((c>>3)&1), kk = c>>4
// ---------------------------------------------------------------------------
__global__ __launch_bounds__(256) void wprep(const float* __restrict__ w,
                                             unsigned short* __restrict__ Wt2) {
  int t = blockIdx.x * 256 + threadIdx.x;  // 0..8191 = n*64 + c
  int n = t >> 6, c = t & 63;
  int kk = c >> 4;
  int lane = (n & 31) + 32 * ((c >> 3) & 1);
  const float* src = w + (size_t)t * 9;
#pragma unroll
  for (int pos = 0; pos < 9; ++pos) {
    int idx = (((pos * 4 + kk) * 4 + (n >> 5)) << 9) + lane * 8 + (c & 7);
    Wt2[idx] = rne_bf16(src[pos]);
  }
}

// ---------------------------------------------------------------------------
// conv, round 10 = R7 (best measured: fused staging, 896 blocks, ONE barrier,
// CS=72) with ONE change: the direct dword-store epilogue is replaced by the
// verified LDS-transpose + full-row v4f epilogue.
// R9 evidence: direct 112-B dword runs into 224-B rows -> partial-line RMW,
// WRITE_SIZE 119MB vs 51MB output (and +15MB RMW FETCH). Every round using
// the transpose epilogue measured WRITE ~51MB (R3/R4/R5).
// The inter-pass barrier is raw s_barrier + lgkmcnt(0) ONLY: fbuf LDS reads
// must finish, but pass-0 GLOBAL stores stay in flight under the pass-1
// transpose (no vmcnt store-drain; stores are to disjoint addresses).
// Accumulation order per output chain identical to the verified kernel.
// ---------------------------------------------------------------------------
__global__ __launch_bounds__(256, 3) void conv(const float* __restrict__ x,
                                               const unsigned short* __restrict__ Wt2,
                                               const float* __restrict__ bias,
                                               float* __restrict__ out) {
  __shared__ __align__(16) char smem[4 * 58 * CS * 2 + 512];
  unsigned short* xs = (unsigned short*)smem;    // [4 rows][58 cols][64 c]
  float* fbuf = (float*)smem;                    // epilogue union: [128][60]
  float* qb = (float*)(smem + 4 * 58 * CS * 2);  // 128 quantized biases

  // bijective XCD swizzle: id -> (xcd = id&7, idx = id>>3), orig = xcd*112+idx
  const int id = blockIdx.x;
  const int orig = (id & 7) * 112 + (id >> 3);
  const int pair = orig % 28, b = orig / 28;
  const int oh0 = pair * 2;
  const int tid = threadIdx.x;
  const int wv = tid >> 6, lane = tid & 63;
  const int lj = lane & 31, lh = lane >> 5;
  const int lj1 = 28 + (lj < 27 ? lj : 27);  // sp-tile1 col offset (clamped)
  const int rw = wv & 1;                     // wave's output row within pair
  const int gg2 = (wv >> 1) * 2;             // wave's first 32-ch group

  // slot decode (448 slots = 4r * 8c8 * 14wq): slot0 = tid, slot1 = 256+tid.
  const int c8 = tid & 7;
  const int jj0 = tid >> 3, jj1 = 32 + (tid >> 3);
  const int r0 = jj0 / 14, wq0 = jj0 - r0 * 14;
  const int r1 = jj1 / 14, wq1 = jj1 - r1 * 14;
  const bool s1v = tid < 192;
  const int h0 = oh0 + r0 - 1, h1 = oh0 + r1 - 1;
  const bool h0v = (unsigned)h0 < 56u;
  const bool h1v = s1v && ((unsigned)h1 < 56u);
  const int off0 = (r0 * 58 + 1 + wq0 * 4) * CS + c8 * 8;
  const int off1 = (r1 * 58 + 1 + wq1 * 4) * CS + c8 * 8;

  const float* xt = x + (size_t)b * 64 * 3136;

  // ---- issue this tile's 16 loads immediately ----
  v4f f0[8], f1[8];
  if (h0v) {
    const float* a = xt + (size_t)(c8 * 8) * 3136 + h0 * 56 + wq0 * 4;
#pragma unroll
    for (int jc = 0; jc < 8; ++jc) f0[jc] = *(const v4f*)&a[(size_t)jc * 3136];
  }
  if (h1v) {
    const float* a = xt + (size_t)(c8 * 8) * 3136 + h1 * 56 + wq1 * 4;
#pragma unroll
    for (int jc = 0; jc < 8; ++jc) f1[jc] = *(const v4f*)&a[(size_t)jc * 3136];
  }

  // ---- W fragments pos0 + bias while waiting ----
  const unsigned short* wt0 = Wt2 + lane * 8;
  v8s wa[4], wb[4];
#define WLOADH(POS, HALF, BUF)                                                 \
  {                                                                            \
    _Pragma("unroll") for (int kk2 = 0; kk2 < 2; ++kk2) {                      \
      _Pragma("unroll") for (int gi = 0; gi < 2; ++gi) {                       \
        BUF[kk2 * 2 + gi] = *(const v8s*)(                                     \
            wt0 + ((((POS)*4 + (HALF)*2 + kk2) * 4 + gg2 + gi) << 9));         \
      }                                                                        \
    }                                                                          \
  }
  WLOADH(0, 0, wa);
  WLOADH(0, 1, wb);
  if (tid < 128) qb[tid] = qbf(bias[tid]);

  v8s z;
#pragma unroll
  for (int e = 0; e < 8; ++e) z[e] = 0;

  // zero col borders (w = -1 and 56): independent of loads
  if (tid < 64) {
    int r = tid >> 4, q = tid & 15;
    int col = (q >> 3) ? 57 : 0;
    *(v8s*)&xs[(r * 58 + col) * CS + (q & 7) * 8] = z;
  }

#define QWRITE(OFF, F)                                                         \
  {                                                                            \
    _Pragma("unroll") for (int k = 0; k < 4; ++k) {                            \
      v8s pk;                                                                  \
      _Pragma("unroll") for (int jc = 0; jc < 8; ++jc)                         \
          pk[jc] = (short)rne_bf16(F[jc][k]);                                  \
      *(v8s*)&xs[(OFF) + k * CS] = pk;                                         \
    }                                                                          \
  }
#define ZWRITE(OFF)                                                            \
  { _Pragma("unroll") for (int k = 0; k < 4; ++k) *(v8s*)&xs[(OFF) + k * CS] = z; }

  // ---- quant + ds_write (first use of f0/f1 -> fine-grained vmcnt wait) ----
  if (h0v) QWRITE(off0, f0) else ZWRITE(off0);
  if (s1v) { if (h1v) QWRITE(off1, f1) else ZWRITE(off1); }

  __syncthreads();  // barrier: xs visible; drains only own loads

  v16f acc[2][2];  // [n-group][sp tile]
#pragma unroll
  for (int a = 0; a < 2; ++a)
#pragma unroll
    for (int s = 0; s < 2; ++s)
#pragma unroll
      for (int e = 0; e < 16; ++e) acc[a][s][e] = 0.0f;

#define COMPH(POS, HALF, BUF)                                                  \
  {                                                                            \
    const int kh = (POS) / 3, kw = (POS) % 3;                                  \
    const unsigned short* p0 = xs + ((rw + kh) * 58 + kw + lj) * CS + lh * 8;  \
    const unsigned short* p1 = xs + ((rw + kh) * 58 + kw + lj1) * CS + lh * 8; \
    _Pragma("unroll") for (int kk2 = 0; kk2 < 2; ++kk2) {                      \
      v8s q0 = *(const v8s*)(p0 + ((HALF)*2 + kk2) * 16);                      \
      v8s q1 = *(const v8s*)(p1 + ((HALF)*2 + kk2) * 16);                      \
      _Pragma("unroll") for (int gi = 0; gi < 2; ++gi) {                       \
        acc[gi][0] = __builtin_amdgcn_mfma_f32_32x32x16_bf16(BUF[kk2 * 2 + gi], q0, acc[gi][0], 0, 0, 0); \
        acc[gi][1] = __builtin_amdgcn_mfma_f32_32x32x16_bf16(BUF[kk2 * 2 + gi], q1, acc[gi][1], 0, 0, 0); \
      }                                                                        \
    }                                                                          \
  }

  COMPH(0, 0, wa); WLOADH(1, 0, wa); COMPH(0, 1, wb); WLOADH(1, 1, wb);
  COMPH(1, 0, wa); WLOADH(2, 0, wa); COMPH(1, 1, wb); WLOADH(2, 1, wb);
  COMPH(2, 0, wa); WLOADH(3, 0, wa); COMPH(2, 1, wb); WLOADH(3, 1, wb);
  COMPH(3, 0, wa); WLOADH(4, 0, wa); COMPH(3, 1, wb); WLOADH(4, 1, wb);
  COMPH(4, 0, wa); WLOADH(5, 0, wa); COMPH(4, 1, wb); WLOADH(5, 1, wb);
  COMPH(5, 0, wa); WLOADH(6, 0, wa); COMPH(5, 1, wb); WLOADH(6, 1, wb);
  COMPH(6, 0, wa); WLOADH(7, 0, wa); COMPH(6, 1, wb); WLOADH(7, 1, wb);
  COMPH(7, 0, wa); WLOADH(8, 0, wa); COMPH(7, 1, wb); WLOADH(8, 1, wb);
  COMPH(8, 0, wa); COMPH(8, 1, wb);

  // ---- epilogue: LDS transpose -> full-row v4f stores (WRITE 119->51 MB) --
  __syncthreads();  // all xs reads done; fbuf may now alias xs
#pragma unroll
  for (int p = 0; p < 2; ++p) {
    if ((wv & 1) == p && lj < 28) {
#pragma unroll
      for (int gi = 0; gi < 2; ++gi) {
#pragma unroll
        for (int e = 0; e < 16; ++e) {
          int chl = (e & 3) + 8 * (e >> 2) + 4 * lh;  // 0..31 (C/D layout)
          int ch = (gg2 + gi) * 32 + chl;
          fbuf[ch * 60 + lj] = acc[gi][0][e];
          fbuf[ch * 60 + 28 + lj] = acc[gi][1][e];
        }
      }
    }
    __syncthreads();
    {
      int ch = tid >> 1, hf = tid & 1;
      float bb = qb[ch];
      const float* srcf = &fbuf[ch * 60 + hf * 28];
      float* dst = out + (size_t)(b * 128 + ch) * 3136 + (oh0 + p) * 56 + hf * 28;
#pragma unroll
      for (int k = 0; k < 7; ++k) {
        v4f v = *(const v4f*)&srcf[k * 4];
        v[0] += bb; v[1] += bb; v[2] += bb; v[3] += bb;
        *(v4f*)&dst[k * 4] = v;
      }
    }
    if (p == 0) {
      // raw barrier, lgkmcnt-only: fbuf LDS reads done, but p0 GLOBAL stores
      // stay in flight under the p1 transpose (no vmcnt store-drain).
      asm volatile("s_waitcnt lgkmcnt(0)" ::: "memory");
      __builtin_amdgcn_s_barrier();
      asm volatile("" ::: "memory");
    }
  }
}

extern "C" void kernel_launch(void* const* d_in, const int* in_sizes, int n_in,
                              void* d_out, int out_size, void* d_ws, size_t ws_size,
                              hipStream_t stream) {
  const float* x = (const float*)d_in[0];     // [32,64,56,56]
  const float* w = (const float*)d_in[1];     // [128,64,3,3]
  const float* bias = (const float*)d_in[2];  // [128]
  float* out = (float*)d_out;                 // [32,128,56,56] fp32

  unsigned short* Wt2 = (unsigned short*)d_ws;  // 147 KB

  wprep<<<32, 256, 0, stream>>>(w, Wt2);
  conv<<<896, 256, 0, stream>>>(x, Wt2, bias, out);
}